// Round 1
// 3921.681 us; speedup vs baseline: 1.9902x; 1.9902x over previous
//
#include <hip/hip_runtime.h>
#include <math.h>

#define SEQ 1024
#define DM  1024
#define NH  16
#define HD  64
#define NL  4
#define FFD 4096
#define VOC 32000
#define EPS 1e-5f

typedef __attribute__((ext_vector_type(8))) short short8;
typedef __attribute__((ext_vector_type(4))) float floatx4;

__device__ __forceinline__ short f2bf(float f) {
    union { float f; unsigned u; } v; v.f = f;
    unsigned r = v.u + 0x7FFFu + ((v.u >> 16) & 1u);   // round-to-nearest-even
    return (short)(r >> 16);
}

// ---------------- embedding + sinusoidal positional encoding ----------------
__global__ __launch_bounds__(256) void embed_kernel(const int* __restrict__ x,
                                                    const float* __restrict__ emb,
                                                    float* __restrict__ h) {
    int s = blockIdx.x;
    int tok = x[s];
    const float c = -logf(10000.0f) / (float)DM;
    for (int d = threadIdx.x; d < DM; d += 256) {
        int j = d >> 1;
        float div = expf((float)(2 * j) * c);
        float ang = (float)s * div;
        float pe = (d & 1) ? cosf(ang) : sinf(ang);
        h[(size_t)s * DM + d] = emb[(size_t)tok * DM + d] + pe;
    }
}

// ---------------- layernorm (one block per row, D=1024) ----------------
__global__ __launch_bounds__(256) void ln_kernel(const float* __restrict__ in,
                                                 float* __restrict__ out,
                                                 const float* __restrict__ w,
                                                 const float* __restrict__ b) {
    __shared__ float red[256];
    int s = blockIdx.x;
    int tid = threadIdx.x;
    const float* row = in + (size_t)s * DM;

    float sum = 0.f;
    for (int d = tid; d < DM; d += 256) sum += row[d];
    red[tid] = sum; __syncthreads();
    for (int off = 128; off > 0; off >>= 1) {
        if (tid < off) red[tid] += red[tid + off];
        __syncthreads();
    }
    float mean = red[0] * (1.0f / DM);
    __syncthreads();

    float vs = 0.f;
    for (int d = tid; d < DM; d += 256) { float t = row[d] - mean; vs += t * t; }
    red[tid] = vs; __syncthreads();
    for (int off = 128; off > 0; off >>= 1) {
        if (tid < off) red[tid] += red[tid + off];
        __syncthreads();
    }
    float rstd = rsqrtf(red[0] * (1.0f / DM) + EPS);

    for (int d = tid; d < DM; d += 256)
        out[(size_t)s * DM + d] = (row[d] - mean) * rstd * w[d] + b[d];
}

// ---------------- bf16 MFMA tiled GEMM: C = op(A[f32] @ B[f32]) ----------------
// A: M x K row-major f32, B: K x N row-major f32. Staged to LDS as bf16.
// flags: 1 = add bias (f32 [N]); 2 = residual add into C (in-place); 4 = relu
#define F_BIAS 1
#define F_RES  2
#define F_RELU 4

#define GBM 128
#define GBN 128
#define GBK 32
// LDS layout per tile: [oct=K/8][row][8] bf16, oct stride padded +24 shorts (48 B)
// so staging ds_write_b128 spreads banks; fragment reads are 256B-contiguous per
// quarter-wave -> conflict-free.
#define OS 1048   // 128*8 + 24, in shorts; byte stride 2096 (16B aligned)

__global__ __launch_bounds__(256) void gemm_kernel(const float* __restrict__ A,
                                                   const float* __restrict__ B,
                                                   const float* __restrict__ bias,
                                                   float* __restrict__ C,
                                                   int M, int N, int K, int flags) {
    __shared__ __align__(16) short As[4 * OS];
    __shared__ __align__(16) short Bs[4 * OS];

    int tid  = threadIdx.x;
    int lane = tid & 63;
    int wave = tid >> 6;                 // 4 waves, 2x2
    int wr = wave >> 1, wc = wave & 1;   // wave computes 64x64 at (wr*64, wc*64)
    int r16 = lane & 15;
    int oct = lane >> 4;                 // k-group 0..3

    int bm = blockIdx.x * GBM;           // x = M-blocks (fast): consecutive blocks
    int bn = blockIdx.y * GBN;           //   share the same B panel -> L2 reuse

    floatx4 acc[4][4];
    #pragma unroll
    for (int i = 0; i < 4; ++i)
        #pragma unroll
        for (int j = 0; j < 4; ++j) acc[i][j] = (floatx4)(0.f);

    for (int k0 = 0; k0 < K; k0 += GBK) {
        // ---- issue global loads into registers (overlaps prior compute) ----
        // A: 512 slots (128 rows x 4 octs), 2 per thread, 8 consecutive k each
        floatx4 av0[2], av1[2];
        #pragma unroll
        for (int l = 0; l < 2; ++l) {
            int f = tid + l * 256;
            int row = f >> 2, o4 = f & 3;
            const float* ap = A + (size_t)(bm + row) * K + k0 + o4 * 8;
            av0[l] = *(const floatx4*)ap;
            av1[l] = *(const floatx4*)(ap + 4);
        }
        // B: 512 slots (128 cols x 4 octs), 2 per thread, 8 k's down a column;
        // each scalar load is coalesced across lanes (consecutive n)
        float bv[2][8];
        #pragma unroll
        for (int l = 0; l < 2; ++l) {
            int f = tid + l * 256;
            int n = f & 127, o = f >> 7;
            const float* bp = B + (size_t)(k0 + o * 8) * N + bn + n;
            #pragma unroll
            for (int j = 0; j < 8; ++j) bv[l][j] = bp[(size_t)j * N];
        }

        __syncthreads();   // previous iteration's fragment reads complete

        // ---- convert + write LDS (bf16) ----
        #pragma unroll
        for (int l = 0; l < 2; ++l) {
            int f = tid + l * 256;
            int row = f >> 2, o4 = f & 3;
            short8 pk;
            #pragma unroll
            for (int q = 0; q < 4; ++q) { pk[q] = f2bf(av0[l][q]); pk[4 + q] = f2bf(av1[l][q]); }
            *(short8*)&As[o4 * OS + row * 8] = pk;
        }
        #pragma unroll
        for (int l = 0; l < 2; ++l) {
            int f = tid + l * 256;
            int n = f & 127, o = f >> 7;
            short8 pk;
            #pragma unroll
            for (int j = 0; j < 8; ++j) pk[j] = f2bf(bv[l][j]);
            *(short8*)&Bs[o * OS + n * 8] = pk;
        }

        __syncthreads();

        // ---- fragments + MFMA ----
        // frag layout: lane holds 8 bf16 at k = oct*8 + j for row/col (lane&15);
        // k-permutation is applied identically to A and B so any bijection is fine.
        short8 af[4], bfr[4];
        #pragma unroll
        for (int i = 0; i < 4; ++i)
            af[i] = *(const short8*)&As[oct * OS + (wr * 64 + i * 16 + r16) * 8];
        #pragma unroll
        for (int j = 0; j < 4; ++j)
            bfr[j] = *(const short8*)&Bs[oct * OS + (wc * 64 + j * 16 + r16) * 8];
        #pragma unroll
        for (int i = 0; i < 4; ++i)
            #pragma unroll
            for (int j = 0; j < 4; ++j)
                acc[i][j] = __builtin_amdgcn_mfma_f32_16x16x32_bf16(af[i], bfr[j], acc[i][j], 0, 0, 0);
    }

    // ---- epilogue: C/D layout col = lane&15, row = oct*4 + reg ----
    #pragma unroll
    for (int i = 0; i < 4; ++i) {
        int rbase = bm + wr * 64 + i * 16 + oct * 4;
        #pragma unroll
        for (int j = 0; j < 4; ++j) {
            int col = bn + wc * 64 + j * 16 + r16;
            float bsv = (flags & F_BIAS) ? bias[col] : 0.f;
            #pragma unroll
            for (int r = 0; r < 4; ++r) {
                float v = acc[i][j][r] + bsv;
                size_t idx = (size_t)(rbase + r) * N + col;
                if (flags & F_RES) v += C[idx];
                if (flags & F_RELU) v = fmaxf(v, 0.f);
                C[idx] = v;
            }
        }
    }
}

// ---------------- causal attention: one block per (query row, head) ----------------
__global__ __launch_bounds__(256) void attn_kernel(const float* __restrict__ q,
                                                   const float* __restrict__ k,
                                                   const float* __restrict__ v,
                                                   float* __restrict__ o) {
    __shared__ float qv[HD];
    __shared__ float sc[SEQ];
    __shared__ float red[256];
    int s = blockIdx.x;
    int hh = blockIdx.y;
    int tid = threadIdx.x;
    int base = hh * HD;

    if (tid < HD) qv[tid] = q[(size_t)s * DM + base + tid];
    __syncthreads();

    const float inv_scale = 0.125f;  // 1/sqrt(HD=64)
    float lmax = -1e30f;
    for (int kk = tid; kk <= s; kk += 256) {
        const float* kr = k + (size_t)kk * DM + base;
        float dot = 0.f;
        #pragma unroll
        for (int d = 0; d < HD; ++d) dot = fmaf(qv[d], kr[d], dot);
        dot *= inv_scale;
        sc[kk] = dot;
        lmax = fmaxf(lmax, dot);
    }
    red[tid] = lmax; __syncthreads();
    for (int off = 128; off > 0; off >>= 1) {
        if (tid < off) red[tid] = fmaxf(red[tid], red[tid + off]);
        __syncthreads();
    }
    float m = red[0];
    __syncthreads();

    float lsum = 0.f;
    for (int kk = tid; kk <= s; kk += 256) {
        float p = expf(sc[kk] - m);
        sc[kk] = p;
        lsum += p;
    }
    red[tid] = lsum; __syncthreads();
    for (int off = 128; off > 0; off >>= 1) {
        if (tid < off) red[tid] += red[tid + off];
        __syncthreads();
    }
    float inv_l = 1.0f / red[0];
    __syncthreads();

    int d = tid & 63, kc = tid >> 6;
    float acc = 0.f;
    for (int kk = kc; kk <= s; kk += 4)
        acc = fmaf(sc[kk], v[(size_t)kk * DM + base + d], acc);
    red[tid] = acc; __syncthreads();
    if (tid < HD) {
        float r2 = red[tid] + red[tid + 64] + red[tid + 128] + red[tid + 192];
        o[(size_t)s * DM + base + tid] = r2 * inv_l;
    }
}

extern "C" void kernel_launch(void* const* d_in, const int* in_sizes, int n_in,
                              void* d_out, int out_size, void* d_ws, size_t ws_size,
                              hipStream_t stream) {
    const int*   x       = (const int*)  d_in[0];
    const float* emb     = (const float*)d_in[1];
    const float* Wq      = (const float*)d_in[2];
    const float* Wk      = (const float*)d_in[3];
    const float* Wv      = (const float*)d_in[4];
    const float* Wo      = (const float*)d_in[5];
    const float* bo      = (const float*)d_in[6];
    const float* ln1_w   = (const float*)d_in[7];
    const float* ln1_b   = (const float*)d_in[8];
    const float* W1      = (const float*)d_in[9];
    const float* b1      = (const float*)d_in[10];
    const float* W2      = (const float*)d_in[11];
    const float* b2      = (const float*)d_in[12];
    const float* ln2_w   = (const float*)d_in[13];
    const float* ln2_b   = (const float*)d_in[14];
    const float* fn_w    = (const float*)d_in[15];
    const float* fn_b    = (const float*)d_in[16];
    const float* lm_head = (const float*)d_in[17];
    float* out = (float*)d_out;   // f32 logits

    // fp32 workspace: h, hn(also attn-out), q, k, v (1M floats each) + ff (4M floats)
    float* h  = (float*)d_ws;
    float* hn = h  + (size_t)SEQ * DM;
    float* qb = hn + (size_t)SEQ * DM;
    float* kb = qb + (size_t)SEQ * DM;
    float* vb = kb + (size_t)SEQ * DM;
    float* fb = vb + (size_t)SEQ * DM;
    float* ab = hn;  // attention output aliases hn (hn dead after V projection)

    embed_kernel<<<SEQ, 256, 0, stream>>>(x, emb, h);

    // grid.x = M-blocks (fast-varying) so co-dispatched blocks share the B panel
    dim3 gD(SEQ / GBM, DM  / GBN);   // 8 x 8
    dim3 gF(SEQ / GBM, FFD / GBN);   // 8 x 32
    dim3 gV(SEQ / GBM, VOC / GBN);   // 8 x 250

    for (int i = 0; i < NL; ++i) {
        ln_kernel<<<SEQ, 256, 0, stream>>>(h, hn, ln1_w + (size_t)i * DM, ln1_b + (size_t)i * DM);
        gemm_kernel<<<gD, 256, 0, stream>>>(hn, Wq + (size_t)i * DM * DM, nullptr, qb, SEQ, DM, DM, 0);
        gemm_kernel<<<gD, 256, 0, stream>>>(hn, Wk + (size_t)i * DM * DM, nullptr, kb, SEQ, DM, DM, 0);
        gemm_kernel<<<gD, 256, 0, stream>>>(hn, Wv + (size_t)i * DM * DM, nullptr, vb, SEQ, DM, DM, 0);
        attn_kernel<<<dim3(SEQ, NH), 256, 0, stream>>>(qb, kb, vb, ab);
        gemm_kernel<<<gD, 256, 0, stream>>>(ab, Wo + (size_t)i * DM * DM, bo + (size_t)i * DM, h,
                                            SEQ, DM, DM, F_BIAS | F_RES);
        ln_kernel<<<SEQ, 256, 0, stream>>>(h, hn, ln2_w + (size_t)i * DM, ln2_b + (size_t)i * DM);
        gemm_kernel<<<gF, 256, 0, stream>>>(hn, W1 + (size_t)i * DM * FFD, b1 + (size_t)i * FFD, fb,
                                            SEQ, FFD, DM, F_BIAS | F_RELU);
        gemm_kernel<<<gD, 256, 0, stream>>>(fb, W2 + (size_t)i * FFD * DM, b2 + (size_t)i * DM, h,
                                            SEQ, DM, FFD, F_BIAS | F_RES);
    }

    ln_kernel<<<SEQ, 256, 0, stream>>>(h, hn, fn_w, fn_b);
    gemm_kernel<<<gV, 256, 0, stream>>>(hn, lm_head, nullptr, out, SEQ, VOC, DM, 0);
}